// Round 1
// baseline (162.797 us; speedup 1.0000x reference)
//
#include <hip/hip_runtime.h>
#include <math.h>

// ROIAlign FPN: feats (2,256,{256,128,64,32}^2) f32 NCHW, proposals (2,512,4).
// Output (1024,256,7,7) f32. One thread per output element.
// S=14 sampling grid, 2x2 adaptive max pool -> 7x7.

__global__ __launch_bounds__(256) void roialign_kernel(
    const float* __restrict__ f0, const float* __restrict__ f1,
    const float* __restrict__ f2, const float* __restrict__ f3,
    const float* __restrict__ props, float* __restrict__ out)
{
    const int idx = blockIdx.x * 256 + threadIdx.x;   // exact grid, no bounds check
    // decode (n, c, ph, pw), pw fastest
    int pw = idx % 7;
    int t  = idx / 7;
    int ph = t % 7;
    t /= 7;
    int c = t & 255;
    int n = t >> 8;        // 0..1023
    int b = n >> 9;        // image index 0..1

    // proposal (unscaled) -> level
    const float px1 = props[n * 4 + 0];
    const float py1 = props[n * 4 + 1];
    const float px2 = props[n * 4 + 2];
    const float py2 = props[n * 4 + 3];
    const float area = (px2 - px1) * (py2 - py1);
    float lf = floorf(2.0f + log2f(sqrtf(area) / 224.0f));
    lf = fminf(fmaxf(lf, 0.0f), 3.0f);
    const int lvl = (int)lf;

    const float* feat;
    int W;
    float scale;
    if (lvl == 0)      { feat = f0; W = 256; scale = 0.25f;    }
    else if (lvl == 1) { feat = f1; W = 128; scale = 0.125f;   }
    else if (lvl == 2) { feat = f2; W = 64;  scale = 0.0625f;  }
    else               { feat = f3; W = 32;  scale = 0.03125f; }

    // scaled proposal
    const float sx1 = px1 * scale;
    const float sy1 = py1 * scale;
    const float sx2 = px2 * scale;
    const float sy2 = py2 * scale;
    const float w_unit = (sx2 - sx1) / 14.0f;
    const float h_unit = (sy2 - sy1) / 14.0f;

    const float Wm1 = (float)(W - 1);
    const float* fb = feat + ((size_t)b * 256 + (size_t)c) * (size_t)(W * W);

    float m = -INFINITY;
    #pragma unroll
    for (int iy = 0; iy < 2; ++iy) {
        const float ry = (float)(2 * ph + iy);
        const float fy = ry * h_unit + h_unit * 0.5f + sy1;
        int y0 = (int)floorf(fy);
        int y1 = y0 + 1;
        const float yc = fminf(fmaxf(fy, 0.0f), Wm1);
        y0 = min(max(y0, 0), W - 1);
        y1 = min(max(y1, 0), W - 1);
        const float y0f = (float)y0;
        const float y1f = (float)y1;
        const float wy0 = y1f - yc;   // pairs with row y0
        const float wy1 = yc - y0f;   // pairs with row y1

        #pragma unroll
        for (int ix = 0; ix < 2; ++ix) {
            const float rx = (float)(2 * pw + ix);
            const float fx = rx * w_unit + w_unit * 0.5f + sx1;
            int x0 = (int)floorf(fx);
            int x1 = x0 + 1;
            const float xc = fminf(fmaxf(fx, 0.0f), Wm1);
            x0 = min(max(x0, 0), W - 1);
            x1 = min(max(x1, 0), W - 1);
            const float x0f = (float)x0;
            const float x1f = (float)x1;
            const float wx0 = x1f - xc;  // pairs with col x0
            const float wx1 = xc - x0f;  // pairs with col x1

            const float la = fb[(size_t)y0 * W + x0];
            const float lb = fb[(size_t)y1 * W + x0];
            const float lc = fb[(size_t)y0 * W + x1];
            const float ld = fb[(size_t)y1 * W + x1];

            const float v = (wx0 * wy0) * la + (wx0 * wy1) * lb
                          + (wx1 * wy0) * lc + (wx1 * wy1) * ld;
            m = fmaxf(m, v);
        }
    }
    out[idx] = m;
}

extern "C" void kernel_launch(void* const* d_in, const int* in_sizes, int n_in,
                              void* d_out, int out_size, void* d_ws, size_t ws_size,
                              hipStream_t stream) {
    const float* f0 = (const float*)d_in[0];
    const float* f1 = (const float*)d_in[1];
    const float* f2 = (const float*)d_in[2];
    const float* f3 = (const float*)d_in[3];
    const float* props = (const float*)d_in[4];
    float* out = (float*)d_out;

    // total outputs = 1024 * 256 * 49 = 12,845,056 = 50176 * 256
    dim3 grid(50176), block(256);
    hipLaunchKernelGGL(roialign_kernel, grid, block, 0, stream,
                       f0, f1, f2, f3, props, out);
}